// Round 4
// baseline (883.699 us; speedup 1.0000x reference)
//
#include <hip/hip_runtime.h>
#include <math.h>

#define BB 128
#define NN 256
#define WW 64
#define DD 128
#define KK 20
#define LL (BB*WW)   // 8192

#define CI3 128      // cov i-tile
#define CJ3 64       // cov j-tile
#define SPLIT 32     // cov split-K chunks
#define BPC (BB/SPLIT) // 4 batches per chunk

// ---------------- Kernel A: per-node means of xr (row n = data[:,n,:] flattened) ----------------
__global__ void k_mean(const float* __restrict__ data, double* __restrict__ mean) {
    int n = blockIdx.x;
    int t = threadIdx.x;                  // 256 threads
    double s = 0.0;
    for (int c = 0; c < LL / 256; ++c) {
        int l = t + c * 256;
        int b = l >> 6, w = l & 63;
        s += (double)data[(b * NN + n) * WW + w];
    }
    for (int off = 32; off; off >>= 1) s += __shfl_down(s, off);
    __shared__ double red[4];
    int lane = t & 63, wid = t >> 6;
    if (lane == 0) red[wid] = s;
    __syncthreads();
    if (t == 0) mean[n] = (red[0] + red[1] + red[2] + red[3]) / (double)LL;
}

// ---------------- Kernel B: emb stats: e_em_i, e_em_j, ||emb||^2 ----------------
__global__ void k_embstats(const float* __restrict__ emb,
                           const float* __restrict__ att_em_i,
                           const float* __restrict__ att_em_j,
                           float* __restrict__ eemi, float* __restrict__ eemj,
                           double* __restrict__ nrm2) {
    int n = blockIdx.x;
    int t = threadIdx.x;                  // 128 threads
    float e = emb[n * DD + t];
    float pi = e * att_em_i[t];
    float pj = e * att_em_j[t];
    double pn = (double)e * (double)e;
    for (int off = 32; off; off >>= 1) {
        pi += __shfl_down(pi, off);
        pj += __shfl_down(pj, off);
        pn += __shfl_down(pn, off);
    }
    __shared__ float ri[2], rj[2];
    __shared__ double rn[2];
    int lane = t & 63, wid = t >> 6;
    if (lane == 0) { ri[wid] = pi; rj[wid] = pj; rn[wid] = pn; }
    __syncthreads();
    if (t == 0) { eemi[n] = ri[0] + ri[1]; eemj[n] = rj[0] + rj[1]; nrm2[n] = rn[0] + rn[1]; }
}

// ---------------- Kernel C: split-K covariance partials, fp32 LDS + fp64 accumulate ------------
// 128x64 tile, 512 threads, each thread 4x4 outputs (rows blocked 4*ti+r, cols strided tj+16*c).
// LDS tiles fp32, float4 reads (4 k/instr), cvt to fp64 in regs. Double-buffered, reg-staged.
__global__ __launch_bounds__(512) void k_cov3(const float* __restrict__ data,
                                              double* __restrict__ covp) {
    const int j0 = blockIdx.x * CJ3;
    const int i0 = blockIdx.y * CI3;
    const int bz = blockIdx.z;
    const int t = threadIdx.x;
    const int ti = t >> 4, tj = t & 15;   // ti 0..31, tj 0..15

    __shared__ float As[2][CI3][68];      // float4-aligned, stride 17 float4
    __shared__ float Bs[2][CJ3][68];

    const int b0 = bz * BPC;
    float4 ra[4], rb[2];

    // ---- reg-stage batch b0 ----
    #pragma unroll
    for (int e = 0; e < 4; ++e) {
        int idx = t + e * 512, row = idx >> 4, q = idx & 15;
        ra[e] = ((const float4*)(data + ((size_t)b0 * NN + i0 + row) * WW))[q];
    }
    #pragma unroll
    for (int e = 0; e < 2; ++e) {
        int idx = t + e * 512, row = idx >> 4, q = idx & 15;
        rb[e] = ((const float4*)(data + ((size_t)b0 * NN + j0 + row) * WW))[q];
    }
    #pragma unroll
    for (int e = 0; e < 4; ++e) {
        int idx = t + e * 512, row = idx >> 4, q = idx & 15;
        *(float4*)&As[0][row][4 * q] = ra[e];
    }
    #pragma unroll
    for (int e = 0; e < 2; ++e) {
        int idx = t + e * 512, row = idx >> 4, q = idx & 15;
        *(float4*)&Bs[0][row][4 * q] = rb[e];
    }
    __syncthreads();

    double acc[4][4] = {};

    #pragma unroll 1
    for (int cb = 0; cb < BPC; ++cb) {
        const int p = cb & 1;

        // issue next chunk's global loads early (latency hides under compute)
        if (cb + 1 < BPC) {
            int nb = b0 + cb + 1;
            #pragma unroll
            for (int e = 0; e < 4; ++e) {
                int idx = t + e * 512, row = idx >> 4, q = idx & 15;
                ra[e] = ((const float4*)(data + ((size_t)nb * NN + i0 + row) * WW))[q];
            }
            #pragma unroll
            for (int e = 0; e < 2; ++e) {
                int idx = t + e * 512, row = idx >> 4, q = idx & 15;
                rb[e] = ((const float4*)(data + ((size_t)nb * NN + j0 + row) * WW))[q];
            }
        }

        // compute chunk cb: 16 k-quads
        #pragma unroll
        for (int q = 0; q < 16; ++q) {
            double bd[4][4];
            #pragma unroll
            for (int c = 0; c < 4; ++c) {
                float4 bf = *(const float4*)&Bs[p][tj + 16 * c][4 * q];
                bd[c][0] = (double)bf.x; bd[c][1] = (double)bf.y;
                bd[c][2] = (double)bf.z; bd[c][3] = (double)bf.w;
            }
            #pragma unroll
            for (int r = 0; r < 4; ++r) {
                float4 af = *(const float4*)&As[p][4 * ti + r][4 * q];
                double a0 = (double)af.x, a1 = (double)af.y;
                double a2 = (double)af.z, a3 = (double)af.w;
                #pragma unroll
                for (int c = 0; c < 4; ++c)
                    acc[r][c] += a0 * bd[c][0] + a1 * bd[c][1]
                               + a2 * bd[c][2] + a3 * bd[c][3];
            }
        }

        // write next chunk into the other buffer
        if (cb + 1 < BPC) {
            #pragma unroll
            for (int e = 0; e < 4; ++e) {
                int idx = t + e * 512, row = idx >> 4, q = idx & 15;
                *(float4*)&As[p ^ 1][row][4 * q] = ra[e];
            }
            #pragma unroll
            for (int e = 0; e < 2; ++e) {
                int idx = t + e * 512, row = idx >> 4, q = idx & 15;
                *(float4*)&Bs[p ^ 1][row][4 * q] = rb[e];
            }
        }
        __syncthreads();
    }

    #pragma unroll
    for (int r = 0; r < 4; ++r)
        #pragma unroll
        for (int c = 0; c < 4; ++c)
            covp[((size_t)bz * NN + i0 + 4 * ti + r) * NN + j0 + tj + 16 * c] = acc[r][c];
}

// ---------------- Kernel C2: reduce split-K partials, subtract mean term ----------------
__global__ void k_cov_reduce(const double* __restrict__ covp,
                             const double* __restrict__ mean,
                             double* __restrict__ cov) {
    int idx = blockIdx.x * 256 + threadIdx.x;   // 0..65535
    int i = idx >> 8, j = idx & 255;
    double s = 0.0;
    #pragma unroll
    for (int z = 0; z < SPLIT; ++z) s += covp[((size_t)z * NN + i) * NN + j];
    s -= (double)LL * mean[i] * mean[j];
    cov[i * NN + j] = s;
}

// ---------------- Kernel D: sim = 0.7*cos + 0.3*corr (fp64) -> fp32, then top-20 per row --------
__global__ void k_sim_topk(const float* __restrict__ emb,
                           const double* __restrict__ nrm2,
                           const double* __restrict__ cov,
                           int* __restrict__ topk) {
    int i = blockIdx.x;
    int t = threadIdx.x;                  // 256 threads; thread t owns column j = t
    __shared__ float embI[DD];
    __shared__ float sim[NN];
    __shared__ float redV[4];
    __shared__ int   redI[4];

    if (t < DD) embI[t] = emb[i * DD + t];
    __syncthreads();

    double dot = 0.0;
    #pragma unroll 4
    for (int d = 0; d < DD; ++d) dot += (double)embI[d] * (double)emb[t * DD + d];
    double cosv = dot / (sqrt(nrm2[i]) * sqrt(nrm2[t]) + 1e-8);
    double stdi = sqrt(cov[i * NN + i] + 1e-8);
    double stdj = sqrt(cov[t * NN + t] + 1e-8);
    double corrv = cov[i * NN + t] / (stdi * stdj + 1e-8);
    sim[t] = (float)(0.7 * cosv + 0.3 * corrv);
    __syncthreads();

    int lane = t & 63, wid = t >> 6;
    for (int k = 0; k < KK; ++k) {
        float v = sim[t];
        int idx = t;
        for (int off = 32; off; off >>= 1) {
            float ov = __shfl_down(v, off);
            int   oi = __shfl_down(idx, off);
            if (ov > v || (ov == v && oi < idx)) { v = ov; idx = oi; }
        }
        if (lane == 0) { redV[wid] = v; redI[wid] = idx; }
        __syncthreads();
        if (t == 0) {
            float bv = redV[0]; int bi = redI[0];
            #pragma unroll
            for (int wv = 1; wv < 4; ++wv)
                if (redV[wv] > bv || (redV[wv] == bv && redI[wv] < bi)) { bv = redV[wv]; bi = redI[wv]; }
            topk[i * KK + k] = bi;
            sim[bi] = -3.4e38f;           // remove from candidates
        }
        __syncthreads();
    }
}

// ---------------- Kernel E: xl = x @ lin_W — 128x128 tile, 8x8 register tile, float4 LDS -------
__global__ __launch_bounds__(256) void k_xl2(const float* __restrict__ data,
                                             const float* __restrict__ linW,
                                             float* __restrict__ xl) {
    const int r0 = blockIdx.x * 128;
    const int t = threadIdx.x;            // 256 threads
    const int ti = t >> 4, tj = t & 15;
    __shared__ float Xs[128][68];         // rows x k, float4-padded
    __shared__ float Wt[DD][68];          // transposed W: Wt[col][k]

    #pragma unroll
    for (int e = 0; e < 8; ++e) {
        int idx = t + e * 256, row = idx >> 4, q = idx & 15;
        float4 v = ((const float4*)(data + (size_t)(r0 + row) * WW))[q];
        *(float4*)&Xs[row][4 * q] = v;
    }
    #pragma unroll
    for (int e = 0; e < 32; ++e) {
        int idx = t + e * 256;            // idx = k*128 + col
        int k = idx >> 7, col = idx & 127;
        Wt[col][k] = linW[idx];
    }
    __syncthreads();

    float acc[8][8] = {};                 // rows 8*ti+r, cols tj+16*c
    #pragma unroll
    for (int q = 0; q < 16; ++q) {
        float4 wb[8];
        #pragma unroll
        for (int c = 0; c < 8; ++c) wb[c] = *(const float4*)&Wt[tj + 16 * c][4 * q];
        #pragma unroll
        for (int r = 0; r < 8; ++r) {
            float4 xa = *(const float4*)&Xs[8 * ti + r][4 * q];
            #pragma unroll
            for (int c = 0; c < 8; ++c)
                acc[r][c] += xa.x * wb[c].x + xa.y * wb[c].y
                           + xa.z * wb[c].z + xa.w * wb[c].w;
        }
    }
    #pragma unroll
    for (int r = 0; r < 8; ++r)
        #pragma unroll
        for (int c = 0; c < 8; ++c)
            xl[(size_t)(r0 + 8 * ti + r) * DD + tj + 16 * c] = acc[r][c];
}

// ---------------- Kernel F: fused attention, batch-local LDS gather ----------------
__global__ __launch_bounds__(512) void k_attn_fused(
        const float* __restrict__ xl, const int* __restrict__ topk,
        const float* __restrict__ att_i, const float* __restrict__ att_j,
        const float* __restrict__ eemi, const float* __restrict__ eemj,
        const float* __restrict__ gnn_bias,
        const float* __restrict__ bn1_g, const float* __restrict__ bn1_b,
        const float* __restrict__ bn2_g, const float* __restrict__ bn2_b,
        const float* __restrict__ emb,
        const float* __restrict__ outW, const float* __restrict__ outb,
        float* __restrict__ out) {
    const int h = blockIdx.x;             // node half: 0 or 1
    const int b = blockIdx.y;             // batch
    const int t = threadIdx.x;            // 512 threads = 8 waves
    const int lane = t & 63, wv = t >> 6;

    __shared__ float xls[NN * DD];        // 128 KB: xl[b]
    __shared__ float sil[NN], sjl[NN];

    {
        const float4* src = (const float4*)(xl + (size_t)b * NN * DD);
        float4* dst = (float4*)xls;
        #pragma unroll
        for (int e = 0; e < 16; ++e) dst[t + e * 512] = src[t + e * 512];
    }
    __syncthreads();

    const float2 ai2 = ((const float2*)att_i)[lane];
    const float2 aj2 = ((const float2*)att_j)[lane];
    for (int r = 0; r < 32; ++r) {
        int j = wv * 32 + r;
        float2 xr = *(const float2*)&xls[j * DD + 2 * lane];
        float pi = xr.x * ai2.x + xr.y * ai2.y;
        float pj = xr.x * aj2.x + xr.y * aj2.y;
        #pragma unroll
        for (int off = 32; off; off >>= 1) {
            pi += __shfl_xor(pi, off);
            pj += __shfl_xor(pj, off);
        }
        if (lane == 0) { sil[j] = pi + eemi[j]; sjl[j] = pj + eemj[j]; }
    }
    __syncthreads();

    const float rbnd = 1.0f / sqrtf(1.0f + 1e-5f);
    const float2 gb2 = ((const float2*)gnn_bias)[lane];
    const float2 g12 = ((const float2*)bn1_g)[lane];
    const float2 b12 = ((const float2*)bn1_b)[lane];
    const float2 g22 = ((const float2*)bn2_g)[lane];
    const float2 b22 = ((const float2*)bn2_b)[lane];
    const float2 ow2 = ((const float2*)outW)[lane];
    const float ob0 = outb[0];

    for (int n = 0; n < 16; ++n) {
        int i = h * 128 + wv * 16 + n;
        int jl = 0;
        float al = -3.4e38f;
        if (lane < KK) {
            jl = topk[i * KK + lane];
            float sc = sil[i] + sjl[jl];
            al = sc > 0.f ? sc : 0.2f * sc;
        }
        float m = al;
        #pragma unroll
        for (int off = 32; off; off >>= 1) m = fmaxf(m, __shfl_xor(m, off));
        float e = (lane < KK) ? expf(al - m) : 0.f;
        float s = e;
        #pragma unroll
        for (int off = 32; off; off >>= 1) s += __shfl_xor(s, off);
        float wgt = e / s;

        float accx = 0.f, accy = 0.f;
        #pragma unroll
        for (int k = 0; k < KK; ++k) {
            int j = __shfl(jl, k);
            float wk = __shfl(wgt, k);
            float2 xv = *(const float2*)&xls[j * DD + 2 * lane];
            accx += wk * xv.x;
            accy += wk * xv.y;
        }

        float2 em = *(const float2*)&emb[(size_t)i * DD + 2 * lane];
        float o0 = (accx + gb2.x) * rbnd * g12.x + b12.x; o0 = fmaxf(o0, 0.f);
        float o1 = (accy + gb2.y) * rbnd * g12.y + b12.y; o1 = fmaxf(o1, 0.f);
        float h0 = o0 * em.x; h0 = h0 * rbnd * g22.x + b22.x; h0 = fmaxf(h0, 0.f);
        float h1 = o1 * em.y; h1 = h1 * rbnd * g22.y + b22.y; h1 = fmaxf(h1, 0.f);

        float p = h0 * ow2.x + h1 * ow2.y;
        #pragma unroll
        for (int off = 32; off; off >>= 1) p += __shfl_xor(p, off);
        if (lane == 0) out[b * NN + i] = p + ob0;
    }
}

extern "C" void kernel_launch(void* const* d_in, const int* in_sizes, int n_in,
                              void* d_out, int out_size, void* d_ws, size_t ws_size,
                              hipStream_t stream) {
    const float* data     = (const float*)d_in[0];
    // d_in[1] = org_edge_index (unused, as in reference)
    const float* emb      = (const float*)d_in[2];
    const float* linW     = (const float*)d_in[3];
    const float* att_i    = (const float*)d_in[4];
    const float* att_j    = (const float*)d_in[5];
    const float* att_em_i = (const float*)d_in[6];
    const float* att_em_j = (const float*)d_in[7];
    const float* gnn_bias = (const float*)d_in[8];
    const float* bn1_g    = (const float*)d_in[9];
    const float* bn1_b    = (const float*)d_in[10];
    const float* bn2_g    = (const float*)d_in[11];
    const float* bn2_b    = (const float*)d_in[12];
    const float* outW     = (const float*)d_in[13];
    const float* outb     = (const float*)d_in[14];
    float* out = (float*)d_out;

    char* ws = (char*)d_ws;
    double* mean  = (double*)(ws + 0);                       // 2 KB
    double* nrm2  = (double*)(ws + 2048);                    // 2 KB
    float*  eemi  = (float*)(ws + 4096);                     // 1 KB
    float*  eemj  = (float*)(ws + 5120);                     // 1 KB
    int*    topk  = (int*)(ws + 8192);                       // 20 KB
    double* cov   = (double*)(ws + 32768);                   // 512 KB
    // covp: 32*256*256*8 = 16.78 MB at +1MB. xl (16 MB) ALIASES it: covp is dead
    // after k_cov_reduce, which precedes k_xl2 in stream order.
    double* covp  = (double*)(ws + (1 << 20));
    float*  xl    = (float*)(ws + (1 << 20));

    k_mean<<<NN, 256, 0, stream>>>(data, mean);
    k_embstats<<<NN, 128, 0, stream>>>(emb, att_em_i, att_em_j, eemi, eemj, nrm2);
    dim3 gc(NN / CJ3, NN / CI3, SPLIT);
    k_cov3<<<gc, 512, 0, stream>>>(data, covp);
    k_cov_reduce<<<NN * NN / 256, 256, 0, stream>>>(covp, mean, cov);
    k_sim_topk<<<NN, 256, 0, stream>>>(emb, nrm2, cov, topk);
    k_xl2<<<(BB * NN) / 128, 256, 0, stream>>>(data, linW, xl);
    dim3 ga(2, BB);
    k_attn_fused<<<ga, 512, 0, stream>>>(xl, topk, att_i, att_j, eemi, eemj, gnn_bias,
                                         bn1_g, bn1_b, bn2_g, bn2_b, emb, outW, outb, out);
}

// Round 5
// 312.620 us; speedup vs baseline: 2.8268x; 2.8268x over previous
//
#include <hip/hip_runtime.h>
#include <math.h>

#define BB 128
#define NN 256
#define WW 64
#define DD 128
#define KK 20
#define LL (BB*WW)   // 8192

#define SPLIT 32     // cov split-K chunks
#define BPC (BB/SPLIT) // 4 batches per chunk

// ---------------- Kernel A: per-node means of xr (row n = data[:,n,:] flattened) ----------------
__global__ void k_mean(const float* __restrict__ data, double* __restrict__ mean) {
    int n = blockIdx.x;
    int t = threadIdx.x;                  // 256 threads
    double s = 0.0;
    for (int c = 0; c < LL / 256; ++c) {
        int l = t + c * 256;
        int b = l >> 6, w = l & 63;
        s += (double)data[(b * NN + n) * WW + w];
    }
    for (int off = 32; off; off >>= 1) s += __shfl_down(s, off);
    __shared__ double red[4];
    int lane = t & 63, wid = t >> 6;
    if (lane == 0) red[wid] = s;
    __syncthreads();
    if (t == 0) mean[n] = (red[0] + red[1] + red[2] + red[3]) / (double)LL;
}

// ---------------- Kernel B: emb stats: e_em_i, e_em_j, ||emb||^2 ----------------
__global__ void k_embstats(const float* __restrict__ emb,
                           const float* __restrict__ att_em_i,
                           const float* __restrict__ att_em_j,
                           float* __restrict__ eemi, float* __restrict__ eemj,
                           double* __restrict__ nrm2) {
    int n = blockIdx.x;
    int t = threadIdx.x;                  // 128 threads
    float e = emb[n * DD + t];
    float pi = e * att_em_i[t];
    float pj = e * att_em_j[t];
    double pn = (double)e * (double)e;
    for (int off = 32; off; off >>= 1) {
        pi += __shfl_down(pi, off);
        pj += __shfl_down(pj, off);
        pn += __shfl_down(pn, off);
    }
    __shared__ float ri[2], rj[2];
    __shared__ double rn[2];
    int lane = t & 63, wid = t >> 6;
    if (lane == 0) { ri[wid] = pi; rj[wid] = pj; rn[wid] = pn; }
    __syncthreads();
    if (t == 0) { eemi[n] = ri[0] + ri[1]; eemj[n] = rj[0] + rj[1]; nrm2[n] = rn[0] + rn[1]; }
}

// ---------------- Kernel C: split-K covariance partials, fp32 LDS + fp64 accumulate ------------
// 64x64 tile, 256 threads, 4x4 fp64 acc per thread (rows ti+16r, cols tj+16c strided).
// Single 35 KB LDS buffer, pad 68 floats (A-read conflict-free, B-read 2-way=free).
// Explicit __launch_bounds__(256,2): 256-VGPR cap, no scratch spill (k_cov3 post-mortem).
__global__ __launch_bounds__(256, 2) void k_cov4(const float* __restrict__ data,
                                                 double* __restrict__ covp) {
    const int j0 = blockIdx.x * 64;
    const int i0 = blockIdx.y * 64;
    const int bz = blockIdx.z;
    const int t = threadIdx.x;
    const int ti = t >> 4, tj = t & 15;   // both 0..15

    __shared__ float As[64][68];
    __shared__ float Bs[64][68];

    const int b0 = bz * BPC;
    float4 ra[4], rb[4];

    // reg-stage chunk 0
    #pragma unroll
    for (int e = 0; e < 4; ++e) {
        int idx = t + e * 256, row = idx >> 4, q = idx & 15;
        ra[e] = ((const float4*)(data + ((size_t)b0 * NN + i0 + row) * WW))[q];
        rb[e] = ((const float4*)(data + ((size_t)b0 * NN + j0 + row) * WW))[q];
    }

    double acc[4][4] = {};

    #pragma unroll 1
    for (int cb = 0; cb < BPC; ++cb) {
        // regs -> LDS
        #pragma unroll
        for (int e = 0; e < 4; ++e) {
            int idx = t + e * 256, row = idx >> 4, q = idx & 15;
            *(float4*)&As[row][4 * q] = ra[e];
            *(float4*)&Bs[row][4 * q] = rb[e];
        }
        __syncthreads();

        // issue next chunk's global loads (independent of LDS; hides under compute)
        if (cb + 1 < BPC) {
            int nb = b0 + cb + 1;
            #pragma unroll
            for (int e = 0; e < 4; ++e) {
                int idx = t + e * 256, row = idx >> 4, q = idx & 15;
                ra[e] = ((const float4*)(data + ((size_t)nb * NN + i0 + row) * WW))[q];
                rb[e] = ((const float4*)(data + ((size_t)nb * NN + j0 + row) * WW))[q];
            }
        }

        // compute: 16 k-quads, 64 fp64 FMAs each
        #pragma unroll
        for (int q = 0; q < 16; ++q) {
            double bd[4][4];
            #pragma unroll
            for (int c = 0; c < 4; ++c) {
                float4 bf = *(const float4*)&Bs[tj + 16 * c][4 * q];
                bd[c][0] = (double)bf.x; bd[c][1] = (double)bf.y;
                bd[c][2] = (double)bf.z; bd[c][3] = (double)bf.w;
            }
            #pragma unroll
            for (int r = 0; r < 4; ++r) {
                float4 af = *(const float4*)&As[ti + 16 * r][4 * q];
                double a0 = (double)af.x, a1 = (double)af.y;
                double a2 = (double)af.z, a3 = (double)af.w;
                #pragma unroll
                for (int c = 0; c < 4; ++c)
                    acc[r][c] += a0 * bd[c][0] + a1 * bd[c][1]
                               + a2 * bd[c][2] + a3 * bd[c][3];
            }
        }
        __syncthreads();
    }

    #pragma unroll
    for (int r = 0; r < 4; ++r)
        #pragma unroll
        for (int c = 0; c < 4; ++c)
            covp[((size_t)bz * NN + i0 + ti + 16 * r) * NN + j0 + tj + 16 * c] = acc[r][c];
}

// ---------------- Kernel C2: reduce split-K partials, subtract mean term ----------------
__global__ void k_cov_reduce(const double* __restrict__ covp,
                             const double* __restrict__ mean,
                             double* __restrict__ cov) {
    int idx = blockIdx.x * 256 + threadIdx.x;   // 0..65535
    int i = idx >> 8, j = idx & 255;
    double s = 0.0;
    #pragma unroll
    for (int z = 0; z < SPLIT; ++z) s += covp[((size_t)z * NN + i) * NN + j];
    s -= (double)LL * mean[i] * mean[j];
    cov[i * NN + j] = s;
}

// ---------------- Kernel D: sim = 0.7*cos + 0.3*corr (fp64) -> fp32, then top-20 per row --------
__global__ void k_sim_topk(const float* __restrict__ emb,
                           const double* __restrict__ nrm2,
                           const double* __restrict__ cov,
                           int* __restrict__ topk) {
    int i = blockIdx.x;
    int t = threadIdx.x;                  // 256 threads; thread t owns column j = t
    __shared__ float embI[DD];
    __shared__ float sim[NN];
    __shared__ float redV[4];
    __shared__ int   redI[4];

    if (t < DD) embI[t] = emb[i * DD + t];
    __syncthreads();

    double dot = 0.0;
    #pragma unroll 4
    for (int d = 0; d < DD; ++d) dot += (double)embI[d] * (double)emb[t * DD + d];
    double cosv = dot / (sqrt(nrm2[i]) * sqrt(nrm2[t]) + 1e-8);
    double stdi = sqrt(cov[i * NN + i] + 1e-8);
    double stdj = sqrt(cov[t * NN + t] + 1e-8);
    double corrv = cov[i * NN + t] / (stdi * stdj + 1e-8);
    sim[t] = (float)(0.7 * cosv + 0.3 * corrv);
    __syncthreads();

    int lane = t & 63, wid = t >> 6;
    for (int k = 0; k < KK; ++k) {
        float v = sim[t];
        int idx = t;
        for (int off = 32; off; off >>= 1) {
            float ov = __shfl_down(v, off);
            int   oi = __shfl_down(idx, off);
            if (ov > v || (ov == v && oi < idx)) { v = ov; idx = oi; }
        }
        if (lane == 0) { redV[wid] = v; redI[wid] = idx; }
        __syncthreads();
        if (t == 0) {
            float bv = redV[0]; int bi = redI[0];
            #pragma unroll
            for (int wv = 1; wv < 4; ++wv)
                if (redV[wv] > bv || (redV[wv] == bv && redI[wv] < bi)) { bv = redV[wv]; bi = redI[wv]; }
            topk[i * KK + k] = bi;
            sim[bi] = -3.4e38f;           // remove from candidates
        }
        __syncthreads();
    }
}

// ---------------- Kernel E: xl = x @ lin_W — 128x128 tile, 8x8 register tile, float4 LDS -------
__global__ __launch_bounds__(256) void k_xl2(const float* __restrict__ data,
                                             const float* __restrict__ linW,
                                             float* __restrict__ xl) {
    const int r0 = blockIdx.x * 128;
    const int t = threadIdx.x;            // 256 threads
    const int ti = t >> 4, tj = t & 15;
    __shared__ float Xs[128][68];         // rows x k, float4-padded
    __shared__ float Wt[DD][68];          // transposed W: Wt[col][k]

    #pragma unroll
    for (int e = 0; e < 8; ++e) {
        int idx = t + e * 256, row = idx >> 4, q = idx & 15;
        float4 v = ((const float4*)(data + (size_t)(r0 + row) * WW))[q];
        *(float4*)&Xs[row][4 * q] = v;
    }
    #pragma unroll
    for (int e = 0; e < 32; ++e) {
        int idx = t + e * 256;            // idx = k*128 + col
        int k = idx >> 7, col = idx & 127;
        Wt[col][k] = linW[idx];
    }
    __syncthreads();

    float acc[8][8] = {};                 // rows 8*ti+r, cols tj+16*c
    #pragma unroll
    for (int q = 0; q < 16; ++q) {
        float4 wb[8];
        #pragma unroll
        for (int c = 0; c < 8; ++c) wb[c] = *(const float4*)&Wt[tj + 16 * c][4 * q];
        #pragma unroll
        for (int r = 0; r < 8; ++r) {
            float4 xa = *(const float4*)&Xs[8 * ti + r][4 * q];
            #pragma unroll
            for (int c = 0; c < 8; ++c)
                acc[r][c] += xa.x * wb[c].x + xa.y * wb[c].y
                           + xa.z * wb[c].z + xa.w * wb[c].w;
        }
    }
    #pragma unroll
    for (int r = 0; r < 8; ++r)
        #pragma unroll
        for (int c = 0; c < 8; ++c)
            xl[(size_t)(r0 + 8 * ti + r) * DD + tj + 16 * c] = acc[r][c];
}

// ---------------- Kernel F: fused attention, batch-local LDS gather ----------------
__global__ __launch_bounds__(512) void k_attn_fused(
        const float* __restrict__ xl, const int* __restrict__ topk,
        const float* __restrict__ att_i, const float* __restrict__ att_j,
        const float* __restrict__ eemi, const float* __restrict__ eemj,
        const float* __restrict__ gnn_bias,
        const float* __restrict__ bn1_g, const float* __restrict__ bn1_b,
        const float* __restrict__ bn2_g, const float* __restrict__ bn2_b,
        const float* __restrict__ emb,
        const float* __restrict__ outW, const float* __restrict__ outb,
        float* __restrict__ out) {
    const int h = blockIdx.x;             // node half: 0 or 1
    const int b = blockIdx.y;             // batch
    const int t = threadIdx.x;            // 512 threads = 8 waves
    const int lane = t & 63, wv = t >> 6;

    __shared__ float xls[NN * DD];        // 128 KB: xl[b]
    __shared__ float sil[NN], sjl[NN];

    {
        const float4* src = (const float4*)(xl + (size_t)b * NN * DD);
        float4* dst = (float4*)xls;
        #pragma unroll
        for (int e = 0; e < 16; ++e) dst[t + e * 512] = src[t + e * 512];
    }
    __syncthreads();

    const float2 ai2 = ((const float2*)att_i)[lane];
    const float2 aj2 = ((const float2*)att_j)[lane];
    for (int r = 0; r < 32; ++r) {
        int j = wv * 32 + r;
        float2 xr = *(const float2*)&xls[j * DD + 2 * lane];
        float pi = xr.x * ai2.x + xr.y * ai2.y;
        float pj = xr.x * aj2.x + xr.y * aj2.y;
        #pragma unroll
        for (int off = 32; off; off >>= 1) {
            pi += __shfl_xor(pi, off);
            pj += __shfl_xor(pj, off);
        }
        if (lane == 0) { sil[j] = pi + eemi[j]; sjl[j] = pj + eemj[j]; }
    }
    __syncthreads();

    const float rbnd = 1.0f / sqrtf(1.0f + 1e-5f);
    const float2 gb2 = ((const float2*)gnn_bias)[lane];
    const float2 g12 = ((const float2*)bn1_g)[lane];
    const float2 b12 = ((const float2*)bn1_b)[lane];
    const float2 g22 = ((const float2*)bn2_g)[lane];
    const float2 b22 = ((const float2*)bn2_b)[lane];
    const float2 ow2 = ((const float2*)outW)[lane];
    const float ob0 = outb[0];

    for (int n = 0; n < 16; ++n) {
        int i = h * 128 + wv * 16 + n;
        int jl = 0;
        float al = -3.4e38f;
        if (lane < KK) {
            jl = topk[i * KK + lane];
            float sc = sil[i] + sjl[jl];
            al = sc > 0.f ? sc : 0.2f * sc;
        }
        float m = al;
        #pragma unroll
        for (int off = 32; off; off >>= 1) m = fmaxf(m, __shfl_xor(m, off));
        float e = (lane < KK) ? expf(al - m) : 0.f;
        float s = e;
        #pragma unroll
        for (int off = 32; off; off >>= 1) s += __shfl_xor(s, off);
        float wgt = e / s;

        float accx = 0.f, accy = 0.f;
        #pragma unroll
        for (int k = 0; k < KK; ++k) {
            int j = __shfl(jl, k);
            float wk = __shfl(wgt, k);
            float2 xv = *(const float2*)&xls[j * DD + 2 * lane];
            accx += wk * xv.x;
            accy += wk * xv.y;
        }

        float2 em = *(const float2*)&emb[(size_t)i * DD + 2 * lane];
        float o0 = (accx + gb2.x) * rbnd * g12.x + b12.x; o0 = fmaxf(o0, 0.f);
        float o1 = (accy + gb2.y) * rbnd * g12.y + b12.y; o1 = fmaxf(o1, 0.f);
        float h0 = o0 * em.x; h0 = h0 * rbnd * g22.x + b22.x; h0 = fmaxf(h0, 0.f);
        float h1 = o1 * em.y; h1 = h1 * rbnd * g22.y + b22.y; h1 = fmaxf(h1, 0.f);

        float p = h0 * ow2.x + h1 * ow2.y;
        #pragma unroll
        for (int off = 32; off; off >>= 1) p += __shfl_xor(p, off);
        if (lane == 0) out[b * NN + i] = p + ob0;
    }
}

extern "C" void kernel_launch(void* const* d_in, const int* in_sizes, int n_in,
                              void* d_out, int out_size, void* d_ws, size_t ws_size,
                              hipStream_t stream) {
    const float* data     = (const float*)d_in[0];
    // d_in[1] = org_edge_index (unused, as in reference)
    const float* emb      = (const float*)d_in[2];
    const float* linW     = (const float*)d_in[3];
    const float* att_i    = (const float*)d_in[4];
    const float* att_j    = (const float*)d_in[5];
    const float* att_em_i = (const float*)d_in[6];
    const float* att_em_j = (const float*)d_in[7];
    const float* gnn_bias = (const float*)d_in[8];
    const float* bn1_g    = (const float*)d_in[9];
    const float* bn1_b    = (const float*)d_in[10];
    const float* bn2_g    = (const float*)d_in[11];
    const float* bn2_b    = (const float*)d_in[12];
    const float* outW     = (const float*)d_in[13];
    const float* outb     = (const float*)d_in[14];
    float* out = (float*)d_out;

    char* ws = (char*)d_ws;
    double* mean  = (double*)(ws + 0);                       // 2 KB
    double* nrm2  = (double*)(ws + 2048);                    // 2 KB
    float*  eemi  = (float*)(ws + 4096);                     // 1 KB
    float*  eemj  = (float*)(ws + 5120);                     // 1 KB
    int*    topk  = (int*)(ws + 8192);                       // 20 KB
    double* cov   = (double*)(ws + 32768);                   // 512 KB
    // covp: 32*256*256*8 = 16.78 MB at +1MB. xl (16 MB) ALIASES it: covp is dead
    // after k_cov_reduce, which precedes k_xl2 in stream order.
    double* covp  = (double*)(ws + (1 << 20));
    float*  xl    = (float*)(ws + (1 << 20));

    k_mean<<<NN, 256, 0, stream>>>(data, mean);
    k_embstats<<<NN, 128, 0, stream>>>(emb, att_em_i, att_em_j, eemi, eemj, nrm2);
    dim3 gc(NN / 64, NN / 64, SPLIT);
    k_cov4<<<gc, 256, 0, stream>>>(data, covp);
    k_cov_reduce<<<NN * NN / 256, 256, 0, stream>>>(covp, mean, cov);
    k_sim_topk<<<NN, 256, 0, stream>>>(emb, nrm2, cov, topk);
    k_xl2<<<(BB * NN) / 128, 256, 0, stream>>>(data, linW, xl);
    dim3 ga(2, BB);
    k_attn_fused<<<ga, 512, 0, stream>>>(xl, topk, att_i, att_j, eemi, eemj, gnn_bias,
                                         bn1_g, bn1_b, bn2_g, bn2_b, emb, outW, outb, out);
}

// Round 6
// 144.275 us; speedup vs baseline: 6.1251x; 2.1668x over previous
//
#include <hip/hip_runtime.h>
#include <math.h>

#define BB 128
#define NN 256
#define WW 64
#define DD 128
#define KK 20
#define LL (BB*WW)   // 8192

#define SPLIT 32     // cov split-K chunks
#define BPC (BB/SPLIT) // 4 batches per chunk

// ---------------- Kernel A: per-node means of xr (row n = data[:,n,:] flattened) ----------------
__global__ void k_mean(const float* __restrict__ data, double* __restrict__ mean) {
    int n = blockIdx.x;
    int t = threadIdx.x;                  // 256 threads
    double s = 0.0;
    for (int c = 0; c < LL / 256; ++c) {
        int l = t + c * 256;
        int b = l >> 6, w = l & 63;
        s += (double)data[(b * NN + n) * WW + w];
    }
    for (int off = 32; off; off >>= 1) s += __shfl_down(s, off);
    __shared__ double red[4];
    int lane = t & 63, wid = t >> 6;
    if (lane == 0) red[wid] = s;
    __syncthreads();
    if (t == 0) mean[n] = (red[0] + red[1] + red[2] + red[3]) / (double)LL;
}

// ---------------- Kernel B: emb stats: e_em_i, e_em_j, ||emb||^2 ----------------
__global__ void k_embstats(const float* __restrict__ emb,
                           const float* __restrict__ att_em_i,
                           const float* __restrict__ att_em_j,
                           float* __restrict__ eemi, float* __restrict__ eemj,
                           double* __restrict__ nrm2) {
    int n = blockIdx.x;
    int t = threadIdx.x;                  // 128 threads
    float e = emb[n * DD + t];
    float pi = e * att_em_i[t];
    float pj = e * att_em_j[t];
    double pn = (double)e * (double)e;
    for (int off = 32; off; off >>= 1) {
        pi += __shfl_down(pi, off);
        pj += __shfl_down(pj, off);
        pn += __shfl_down(pn, off);
    }
    __shared__ float ri[2], rj[2];
    __shared__ double rn[2];
    int lane = t & 63, wid = t >> 6;
    if (lane == 0) { ri[wid] = pi; rj[wid] = pj; rn[wid] = pn; }
    __syncthreads();
    if (t == 0) { eemi[n] = ri[0] + ri[1]; eemj[n] = rj[0] + rj[1]; nrm2[n] = rn[0] + rn[1]; }
}

// ---------------- Kernel C: split-K covariance partials, fp32 LDS + fp64 accumulate ------------
// 64x64 tile, 256 threads, 4x4 fp64 acc per thread (rows ti+16r, cols tj+16c strided).
// NO register prefetch across the compute loop (k_cov3/k_cov4 post-mortem: >128 live VGPRs
// spilled ~550 MB of scratch per dispatch). Live set in compute ~= 85 VGPRs.
__global__ __launch_bounds__(256) void k_cov5(const float* __restrict__ data,
                                              double* __restrict__ covp) {
    const int j0 = blockIdx.x * 64;
    const int i0 = blockIdx.y * 64;
    const int bz = blockIdx.z;
    const int t = threadIdx.x;
    const int ti = t >> 4, tj = t & 15;   // both 0..15

    __shared__ float As[64][68];          // pad 68: A-read conflict-free, B-read 2-way (free)
    __shared__ float Bs[64][68];

    const int b0 = bz * BPC;
    double acc[4][4] = {};

    #pragma unroll 1
    for (int cb = 0; cb < BPC; ++cb) {
        const int b = b0 + cb;
        // stage chunk: global -> (short-lived regs) -> LDS; regs dead before compute
        #pragma unroll
        for (int e = 0; e < 4; ++e) {
            int idx = t + e * 256, row = idx >> 4, q = idx & 15;
            float4 va = ((const float4*)(data + ((size_t)b * NN + i0 + row) * WW))[q];
            float4 vb = ((const float4*)(data + ((size_t)b * NN + j0 + row) * WW))[q];
            *(float4*)&As[row][4 * q] = va;
            *(float4*)&Bs[row][4 * q] = vb;
        }
        __syncthreads();

        // compute: 16 k-quads, 64 fp64 FMAs each
        #pragma unroll 2
        for (int q = 0; q < 16; ++q) {
            double bd[4][4];
            #pragma unroll
            for (int c = 0; c < 4; ++c) {
                float4 bf = *(const float4*)&Bs[tj + 16 * c][4 * q];
                bd[c][0] = (double)bf.x; bd[c][1] = (double)bf.y;
                bd[c][2] = (double)bf.z; bd[c][3] = (double)bf.w;
            }
            #pragma unroll
            for (int r = 0; r < 4; ++r) {
                float4 af = *(const float4*)&As[ti + 16 * r][4 * q];
                double a0 = (double)af.x, a1 = (double)af.y;
                double a2 = (double)af.z, a3 = (double)af.w;
                #pragma unroll
                for (int c = 0; c < 4; ++c)
                    acc[r][c] += a0 * bd[c][0] + a1 * bd[c][1]
                               + a2 * bd[c][2] + a3 * bd[c][3];
            }
        }
        __syncthreads();
    }

    #pragma unroll
    for (int r = 0; r < 4; ++r)
        #pragma unroll
        for (int c = 0; c < 4; ++c)
            covp[((size_t)bz * NN + i0 + ti + 16 * r) * NN + j0 + tj + 16 * c] = acc[r][c];
}

// ---------------- Kernel C2: reduce split-K partials, subtract mean term ----------------
__global__ void k_cov_reduce(const double* __restrict__ covp,
                             const double* __restrict__ mean,
                             double* __restrict__ cov) {
    int idx = blockIdx.x * 256 + threadIdx.x;   // 0..65535
    int i = idx >> 8, j = idx & 255;
    double s = 0.0;
    #pragma unroll
    for (int z = 0; z < SPLIT; ++z) s += covp[((size_t)z * NN + i) * NN + j];
    s -= (double)LL * mean[i] * mean[j];
    cov[i * NN + j] = s;
}

// ---------------- Kernel D: sim = 0.7*cos + 0.3*corr (fp64) -> fp32, then top-20 per row --------
__global__ void k_sim_topk(const float* __restrict__ emb,
                           const double* __restrict__ nrm2,
                           const double* __restrict__ cov,
                           int* __restrict__ topk) {
    int i = blockIdx.x;
    int t = threadIdx.x;                  // 256 threads; thread t owns column j = t
    __shared__ float embI[DD];
    __shared__ float sim[NN];
    __shared__ float redV[4];
    __shared__ int   redI[4];

    if (t < DD) embI[t] = emb[i * DD + t];
    __syncthreads();

    double dot = 0.0;
    #pragma unroll 4
    for (int d = 0; d < DD; ++d) dot += (double)embI[d] * (double)emb[t * DD + d];
    double cosv = dot / (sqrt(nrm2[i]) * sqrt(nrm2[t]) + 1e-8);
    double stdi = sqrt(cov[i * NN + i] + 1e-8);
    double stdj = sqrt(cov[t * NN + t] + 1e-8);
    double corrv = cov[i * NN + t] / (stdi * stdj + 1e-8);
    sim[t] = (float)(0.7 * cosv + 0.3 * corrv);
    __syncthreads();

    int lane = t & 63, wid = t >> 6;
    for (int k = 0; k < KK; ++k) {
        float v = sim[t];
        int idx = t;
        for (int off = 32; off; off >>= 1) {
            float ov = __shfl_down(v, off);
            int   oi = __shfl_down(idx, off);
            if (ov > v || (ov == v && oi < idx)) { v = ov; idx = oi; }
        }
        if (lane == 0) { redV[wid] = v; redI[wid] = idx; }
        __syncthreads();
        if (t == 0) {
            float bv = redV[0]; int bi = redI[0];
            #pragma unroll
            for (int wv = 1; wv < 4; ++wv)
                if (redV[wv] > bv || (redV[wv] == bv && redI[wv] < bi)) { bv = redV[wv]; bi = redI[wv]; }
            topk[i * KK + k] = bi;
            sim[bi] = -3.4e38f;           // remove from candidates
        }
        __syncthreads();
    }
}

// ---------------- Kernel E: xl = x @ lin_W — 128x128 tile, 8x8 register tile, float4 LDS -------
__global__ __launch_bounds__(256) void k_xl2(const float* __restrict__ data,
                                             const float* __restrict__ linW,
                                             float* __restrict__ xl) {
    const int r0 = blockIdx.x * 128;
    const int t = threadIdx.x;            // 256 threads
    const int ti = t >> 4, tj = t & 15;
    __shared__ float Xs[128][68];         // rows x k, float4-padded
    __shared__ float Wt[DD][68];          // transposed W: Wt[col][k]

    #pragma unroll
    for (int e = 0; e < 8; ++e) {
        int idx = t + e * 256, row = idx >> 4, q = idx & 15;
        float4 v = ((const float4*)(data + (size_t)(r0 + row) * WW))[q];
        *(float4*)&Xs[row][4 * q] = v;
    }
    #pragma unroll
    for (int e = 0; e < 32; ++e) {
        int idx = t + e * 256;            // idx = k*128 + col
        int k = idx >> 7, col = idx & 127;
        Wt[col][k] = linW[idx];
    }
    __syncthreads();

    float acc[8][8] = {};                 // rows 8*ti+r, cols tj+16*c
    #pragma unroll
    for (int q = 0; q < 16; ++q) {
        float4 wb[8];
        #pragma unroll
        for (int c = 0; c < 8; ++c) wb[c] = *(const float4*)&Wt[tj + 16 * c][4 * q];
        #pragma unroll
        for (int r = 0; r < 8; ++r) {
            float4 xa = *(const float4*)&Xs[8 * ti + r][4 * q];
            #pragma unroll
            for (int c = 0; c < 8; ++c)
                acc[r][c] += xa.x * wb[c].x + xa.y * wb[c].y
                           + xa.z * wb[c].z + xa.w * wb[c].w;
        }
    }
    #pragma unroll
    for (int r = 0; r < 8; ++r)
        #pragma unroll
        for (int c = 0; c < 8; ++c)
            xl[(size_t)(r0 + 8 * ti + r) * DD + tj + 16 * c] = acc[r][c];
}

// ---------------- Kernel F: fused attention, batch-local LDS gather ----------------
__global__ __launch_bounds__(512) void k_attn_fused(
        const float* __restrict__ xl, const int* __restrict__ topk,
        const float* __restrict__ att_i, const float* __restrict__ att_j,
        const float* __restrict__ eemi, const float* __restrict__ eemj,
        const float* __restrict__ gnn_bias,
        const float* __restrict__ bn1_g, const float* __restrict__ bn1_b,
        const float* __restrict__ bn2_g, const float* __restrict__ bn2_b,
        const float* __restrict__ emb,
        const float* __restrict__ outW, const float* __restrict__ outb,
        float* __restrict__ out) {
    const int h = blockIdx.x;             // node half: 0 or 1
    const int b = blockIdx.y;             // batch
    const int t = threadIdx.x;            // 512 threads = 8 waves
    const int lane = t & 63, wv = t >> 6;

    __shared__ float xls[NN * DD];        // 128 KB: xl[b]
    __shared__ float sil[NN], sjl[NN];

    {
        const float4* src = (const float4*)(xl + (size_t)b * NN * DD);
        float4* dst = (float4*)xls;
        #pragma unroll
        for (int e = 0; e < 16; ++e) dst[t + e * 512] = src[t + e * 512];
    }
    __syncthreads();

    const float2 ai2 = ((const float2*)att_i)[lane];
    const float2 aj2 = ((const float2*)att_j)[lane];
    for (int r = 0; r < 32; ++r) {
        int j = wv * 32 + r;
        float2 xr = *(const float2*)&xls[j * DD + 2 * lane];
        float pi = xr.x * ai2.x + xr.y * ai2.y;
        float pj = xr.x * aj2.x + xr.y * aj2.y;
        #pragma unroll
        for (int off = 32; off; off >>= 1) {
            pi += __shfl_xor(pi, off);
            pj += __shfl_xor(pj, off);
        }
        if (lane == 0) { sil[j] = pi + eemi[j]; sjl[j] = pj + eemj[j]; }
    }
    __syncthreads();

    const float rbnd = 1.0f / sqrtf(1.0f + 1e-5f);
    const float2 gb2 = ((const float2*)gnn_bias)[lane];
    const float2 g12 = ((const float2*)bn1_g)[lane];
    const float2 b12 = ((const float2*)bn1_b)[lane];
    const float2 g22 = ((const float2*)bn2_g)[lane];
    const float2 b22 = ((const float2*)bn2_b)[lane];
    const float2 ow2 = ((const float2*)outW)[lane];
    const float ob0 = outb[0];

    for (int n = 0; n < 16; ++n) {
        int i = h * 128 + wv * 16 + n;
        int jl = 0;
        float al = -3.4e38f;
        if (lane < KK) {
            jl = topk[i * KK + lane];
            float sc = sil[i] + sjl[jl];
            al = sc > 0.f ? sc : 0.2f * sc;
        }
        float m = al;
        #pragma unroll
        for (int off = 32; off; off >>= 1) m = fmaxf(m, __shfl_xor(m, off));
        float e = (lane < KK) ? expf(al - m) : 0.f;
        float s = e;
        #pragma unroll
        for (int off = 32; off; off >>= 1) s += __shfl_xor(s, off);
        float wgt = e / s;

        float accx = 0.f, accy = 0.f;
        #pragma unroll
        for (int k = 0; k < KK; ++k) {
            int j = __shfl(jl, k);
            float wk = __shfl(wgt, k);
            float2 xv = *(const float2*)&xls[j * DD + 2 * lane];
            accx += wk * xv.x;
            accy += wk * xv.y;
        }

        float2 em = *(const float2*)&emb[(size_t)i * DD + 2 * lane];
        float o0 = (accx + gb2.x) * rbnd * g12.x + b12.x; o0 = fmaxf(o0, 0.f);
        float o1 = (accy + gb2.y) * rbnd * g12.y + b12.y; o1 = fmaxf(o1, 0.f);
        float h0 = o0 * em.x; h0 = h0 * rbnd * g22.x + b22.x; h0 = fmaxf(h0, 0.f);
        float h1 = o1 * em.y; h1 = h1 * rbnd * g22.y + b22.y; h1 = fmaxf(h1, 0.f);

        float p = h0 * ow2.x + h1 * ow2.y;
        #pragma unroll
        for (int off = 32; off; off >>= 1) p += __shfl_xor(p, off);
        if (lane == 0) out[b * NN + i] = p + ob0;
    }
}

extern "C" void kernel_launch(void* const* d_in, const int* in_sizes, int n_in,
                              void* d_out, int out_size, void* d_ws, size_t ws_size,
                              hipStream_t stream) {
    const float* data     = (const float*)d_in[0];
    // d_in[1] = org_edge_index (unused, as in reference)
    const float* emb      = (const float*)d_in[2];
    const float* linW     = (const float*)d_in[3];
    const float* att_i    = (const float*)d_in[4];
    const float* att_j    = (const float*)d_in[5];
    const float* att_em_i = (const float*)d_in[6];
    const float* att_em_j = (const float*)d_in[7];
    const float* gnn_bias = (const float*)d_in[8];
    const float* bn1_g    = (const float*)d_in[9];
    const float* bn1_b    = (const float*)d_in[10];
    const float* bn2_g    = (const float*)d_in[11];
    const float* bn2_b    = (const float*)d_in[12];
    const float* outW     = (const float*)d_in[13];
    const float* outb     = (const float*)d_in[14];
    float* out = (float*)d_out;

    char* ws = (char*)d_ws;
    double* mean  = (double*)(ws + 0);                       // 2 KB
    double* nrm2  = (double*)(ws + 2048);                    // 2 KB
    float*  eemi  = (float*)(ws + 4096);                     // 1 KB
    float*  eemj  = (float*)(ws + 5120);                     // 1 KB
    int*    topk  = (int*)(ws + 8192);                       // 20 KB
    double* cov   = (double*)(ws + 32768);                   // 512 KB
    // covp: 32*256*256*8 = 16.78 MB at +1MB. xl (16 MB) ALIASES it: covp is dead
    // after k_cov_reduce, which precedes k_xl2 in stream order.
    double* covp  = (double*)(ws + (1 << 20));
    float*  xl    = (float*)(ws + (1 << 20));

    k_mean<<<NN, 256, 0, stream>>>(data, mean);
    k_embstats<<<NN, 128, 0, stream>>>(emb, att_em_i, att_em_j, eemi, eemj, nrm2);
    dim3 gc(NN / 64, NN / 64, SPLIT);
    k_cov5<<<gc, 256, 0, stream>>>(data, covp);
    k_cov_reduce<<<NN * NN / 256, 256, 0, stream>>>(covp, mean, cov);
    k_sim_topk<<<NN, 256, 0, stream>>>(emb, nrm2, cov, topk);
    k_xl2<<<(BB * NN) / 128, 256, 0, stream>>>(data, linW, xl);
    dim3 ga(2, BB);
    k_attn_fused<<<ga, 512, 0, stream>>>(xl, topk, att_i, att_j, eemi, eemj, gnn_bias,
                                         bn1_g, bn1_b, bn2_g, bn2_b, emb, outW, outb, out);
}

// Round 7
// 121.040 us; speedup vs baseline: 7.3009x; 1.1920x over previous
//
#include <hip/hip_runtime.h>
#include <math.h>

#define BB 128
#define NN 256
#define WW 64
#define DD 128
#define KK 20
#define LL (BB*WW)   // 8192

#define SPLIT 32     // cov split-K chunks
#define BPC (BB/SPLIT) // 4 batches per chunk

// ---------------- Kernel A: per-node means of xr (row n = data[:,n,:] flattened) ----------------
__global__ void k_mean(const float* __restrict__ data, double* __restrict__ mean) {
    int n = blockIdx.x;
    int t = threadIdx.x;                  // 256 threads
    double s = 0.0;
    for (int c = 0; c < LL / 256; ++c) {
        int l = t + c * 256;
        int b = l >> 6, w = l & 63;
        s += (double)data[(b * NN + n) * WW + w];
    }
    for (int off = 32; off; off >>= 1) s += __shfl_down(s, off);
    __shared__ double red[4];
    int lane = t & 63, wid = t >> 6;
    if (lane == 0) red[wid] = s;
    __syncthreads();
    if (t == 0) mean[n] = (red[0] + red[1] + red[2] + red[3]) / (double)LL;
}

// ---------------- Kernel B: emb stats: e_em_i, e_em_j, ||emb||^2 ----------------
__global__ void k_embstats(const float* __restrict__ emb,
                           const float* __restrict__ att_em_i,
                           const float* __restrict__ att_em_j,
                           float* __restrict__ eemi, float* __restrict__ eemj,
                           double* __restrict__ nrm2) {
    int n = blockIdx.x;
    int t = threadIdx.x;                  // 128 threads
    float e = emb[n * DD + t];
    float pi = e * att_em_i[t];
    float pj = e * att_em_j[t];
    double pn = (double)e * (double)e;
    for (int off = 32; off; off >>= 1) {
        pi += __shfl_down(pi, off);
        pj += __shfl_down(pj, off);
        pn += __shfl_down(pn, off);
    }
    __shared__ float ri[2], rj[2];
    __shared__ double rn[2];
    int lane = t & 63, wid = t >> 6;
    if (lane == 0) { ri[wid] = pi; rj[wid] = pj; rn[wid] = pn; }
    __syncthreads();
    if (t == 0) { eemi[n] = ri[0] + ri[1]; eemj[n] = rj[0] + rj[1]; nrm2[n] = rn[0] + rn[1]; }
}

// ---------------- Kernel C: split-K covariance partials, fp32 LDS + fp64 accumulate ------------
__global__ __launch_bounds__(256) void k_cov5(const float* __restrict__ data,
                                              double* __restrict__ covp) {
    const int j0 = blockIdx.x * 64;
    const int i0 = blockIdx.y * 64;
    const int bz = blockIdx.z;
    const int t = threadIdx.x;
    const int ti = t >> 4, tj = t & 15;   // both 0..15

    __shared__ float As[64][68];
    __shared__ float Bs[64][68];

    const int b0 = bz * BPC;
    double acc[4][4] = {};

    #pragma unroll 1
    for (int cb = 0; cb < BPC; ++cb) {
        const int b = b0 + cb;
        #pragma unroll
        for (int e = 0; e < 4; ++e) {
            int idx = t + e * 256, row = idx >> 4, q = idx & 15;
            float4 va = ((const float4*)(data + ((size_t)b * NN + i0 + row) * WW))[q];
            float4 vb = ((const float4*)(data + ((size_t)b * NN + j0 + row) * WW))[q];
            *(float4*)&As[row][4 * q] = va;
            *(float4*)&Bs[row][4 * q] = vb;
        }
        __syncthreads();

        #pragma unroll 2
        for (int q = 0; q < 16; ++q) {
            double bd[4][4];
            #pragma unroll
            for (int c = 0; c < 4; ++c) {
                float4 bf = *(const float4*)&Bs[tj + 16 * c][4 * q];
                bd[c][0] = (double)bf.x; bd[c][1] = (double)bf.y;
                bd[c][2] = (double)bf.z; bd[c][3] = (double)bf.w;
            }
            #pragma unroll
            for (int r = 0; r < 4; ++r) {
                float4 af = *(const float4*)&As[ti + 16 * r][4 * q];
                double a0 = (double)af.x, a1 = (double)af.y;
                double a2 = (double)af.z, a3 = (double)af.w;
                #pragma unroll
                for (int c = 0; c < 4; ++c)
                    acc[r][c] += a0 * bd[c][0] + a1 * bd[c][1]
                               + a2 * bd[c][2] + a3 * bd[c][3];
            }
        }
        __syncthreads();
    }

    #pragma unroll
    for (int r = 0; r < 4; ++r)
        #pragma unroll
        for (int c = 0; c < 4; ++c)
            covp[((size_t)bz * NN + i0 + ti + 16 * r) * NN + j0 + tj + 16 * c] = acc[r][c];
}

// ---------------- Kernel C2: reduce split-K partials, subtract mean term ----------------
__global__ void k_cov_reduce(const double* __restrict__ covp,
                             const double* __restrict__ mean,
                             double* __restrict__ cov) {
    int idx = blockIdx.x * 256 + threadIdx.x;   // 0..65535
    int i = idx >> 8, j = idx & 255;
    double s = 0.0;
    #pragma unroll
    for (int z = 0; z < SPLIT; ++z) s += covp[((size_t)z * NN + i) * NN + j];
    s -= (double)LL * mean[i] * mean[j];
    cov[i * NN + j] = s;
}

// ---------------- Kernel D: sim = 0.7*cos + 0.3*corr (fp64) -> fp32, then top-20 per row --------
__global__ void k_sim_topk(const float* __restrict__ emb,
                           const double* __restrict__ nrm2,
                           const double* __restrict__ cov,
                           int* __restrict__ topk) {
    int i = blockIdx.x;
    int t = threadIdx.x;                  // 256 threads; thread t owns column j = t
    __shared__ float embI[DD];
    __shared__ float sim[NN];
    __shared__ float redV[4];
    __shared__ int   redI[4];

    if (t < DD) embI[t] = emb[i * DD + t];
    __syncthreads();

    double dot = 0.0;
    #pragma unroll 4
    for (int d = 0; d < DD; ++d) dot += (double)embI[d] * (double)emb[t * DD + d];
    double cosv = dot / (sqrt(nrm2[i]) * sqrt(nrm2[t]) + 1e-8);
    double stdi = sqrt(cov[i * NN + i] + 1e-8);
    double stdj = sqrt(cov[t * NN + t] + 1e-8);
    double corrv = cov[i * NN + t] / (stdi * stdj + 1e-8);
    sim[t] = (float)(0.7 * cosv + 0.3 * corrv);
    __syncthreads();

    int lane = t & 63, wid = t >> 6;
    for (int k = 0; k < KK; ++k) {
        float v = sim[t];
        int idx = t;
        for (int off = 32; off; off >>= 1) {
            float ov = __shfl_down(v, off);
            int   oi = __shfl_down(idx, off);
            if (ov > v || (ov == v && oi < idx)) { v = ov; idx = oi; }
        }
        if (lane == 0) { redV[wid] = v; redI[wid] = idx; }
        __syncthreads();
        if (t == 0) {
            float bv = redV[0]; int bi = redI[0];
            #pragma unroll
            for (int wv = 1; wv < 4; ++wv)
                if (redV[wv] > bv || (redV[wv] == bv && redI[wv] < bi)) { bv = redV[wv]; bi = redI[wv]; }
            topk[i * KK + k] = bi;
            sim[bi] = -3.4e38f;           // remove from candidates
        }
        __syncthreads();
    }
}

// ---------------- Kernel E: xl = x @ lin_W — 128x128 tile, 8x8 register tile, float4 LDS -------
__global__ __launch_bounds__(256) void k_xl2(const float* __restrict__ data,
                                             const float* __restrict__ linW,
                                             float* __restrict__ xl) {
    const int r0 = blockIdx.x * 128;
    const int t = threadIdx.x;            // 256 threads
    const int ti = t >> 4, tj = t & 15;
    __shared__ float Xs[128][68];         // rows x k, float4-padded
    __shared__ float Wt[DD][68];          // transposed W: Wt[col][k]

    #pragma unroll
    for (int e = 0; e < 8; ++e) {
        int idx = t + e * 256, row = idx >> 4, q = idx & 15;
        float4 v = ((const float4*)(data + (size_t)(r0 + row) * WW))[q];
        *(float4*)&Xs[row][4 * q] = v;
    }
    #pragma unroll
    for (int e = 0; e < 32; ++e) {
        int idx = t + e * 256;            // idx = k*128 + col
        int k = idx >> 7, col = idx & 127;
        Wt[col][k] = linW[idx];
    }
    __syncthreads();

    float acc[8][8] = {};                 // rows 8*ti+r, cols tj+16*c
    #pragma unroll
    for (int q = 0; q < 16; ++q) {
        float4 wb[8];
        #pragma unroll
        for (int c = 0; c < 8; ++c) wb[c] = *(const float4*)&Wt[tj + 16 * c][4 * q];
        #pragma unroll
        for (int r = 0; r < 8; ++r) {
            float4 xa = *(const float4*)&Xs[8 * ti + r][4 * q];
            #pragma unroll
            for (int c = 0; c < 8; ++c)
                acc[r][c] += xa.x * wb[c].x + xa.y * wb[c].y
                           + xa.z * wb[c].z + xa.w * wb[c].w;
        }
    }
    #pragma unroll
    for (int r = 0; r < 8; ++r)
        #pragma unroll
        for (int c = 0; c < 8; ++c)
            xl[(size_t)(r0 + 8 * ti + r) * DD + tj + 16 * c] = acc[r][c];
}

// ---------------- Kernel E2: sil/sjl = xl.att_{i,j} + eem (one wave per row) ----------------
__global__ void k_sij(const float* __restrict__ xl,
                      const float* __restrict__ att_i,
                      const float* __restrict__ att_j,
                      const float* __restrict__ eemi,
                      const float* __restrict__ eemj,
                      float* __restrict__ sil, float* __restrict__ sjl) {
    int t = threadIdx.x;                  // 256 threads = 4 waves, one row each
    int lane = t & 63, wv = t >> 6;
    int v = blockIdx.x * 4 + wv;
    float x0 = xl[(size_t)v * DD + lane];
    float x1 = xl[(size_t)v * DD + 64 + lane];
    float pi = x0 * att_i[lane] + x1 * att_i[64 + lane];
    float pj = x0 * att_j[lane] + x1 * att_j[64 + lane];
    #pragma unroll
    for (int off = 32; off; off >>= 1) { pi += __shfl_down(pi, off); pj += __shfl_down(pj, off); }
    if (lane == 0) {
        int i = v & (NN - 1);
        sil[v] = pi + eemi[i];
        sjl[v] = pj + eemj[i];
    }
}

// ---------------- Kernel F: fused attention v2 ----------------
// Block (h, b): stage xl[b] (128 KB) in LDS; pre-phase: threads 0..127 compute the
// 20-edge softmax for their node scalar/thread-local (no shuffles) -> packed (j,w) in LDS;
// gather: half-wave per node, lane owns 4 dims (ds_read_b128), 20 DS-ops/node; epilogue fused.
__global__ __launch_bounds__(512) void k_attn2(
        const float* __restrict__ xl, const int* __restrict__ topk,
        const float* __restrict__ sil, const float* __restrict__ sjl,
        const float* __restrict__ gnn_bias,
        const float* __restrict__ bn1_g, const float* __restrict__ bn1_b,
        const float* __restrict__ bn2_g, const float* __restrict__ bn2_b,
        const float* __restrict__ emb,
        const float* __restrict__ outW, const float* __restrict__ outb,
        float* __restrict__ out) {
    const int h = blockIdx.x;             // node half: 0 or 1
    const int b = blockIdx.y;             // batch
    const int t = threadIdx.x;            // 512 threads = 8 waves
    const int lane = t & 63, wv = t >> 6;
    const int q = lane & 31, half = lane >> 5;

    __shared__ float xls[NN * DD];        // 128 KB: xl[b]
    __shared__ int2 jwS[128 * KK];        // 20 KB: packed (j, w) per local node

    // ---- stage xl[b] (coalesced float4) ----
    {
        const float4* src = (const float4*)(xl + (size_t)b * NN * DD);
        float4* dst = (float4*)xls;
        #pragma unroll
        for (int e = 0; e < 16; ++e) dst[t + e * 512] = src[t + e * 512];
    }

    // ---- pre-phase: per-node softmax, scalar per thread (nodes h*128 .. h*128+127) ----
    if (t < 128) {
        int i = h * 128 + t;
        float si = sil[b * NN + i];
        int jj[KK]; float aa[KK];
        float amax = -3.4e38f;
        #pragma unroll
        for (int k = 0; k < KK; ++k) {
            int j = topk[i * KK + k];
            jj[k] = j;
            float a = si + sjl[b * NN + j];
            a = a > 0.f ? a : 0.2f * a;   // leaky relu
            aa[k] = a;
            amax = fmaxf(amax, a);
        }
        float den = 0.f;
        #pragma unroll
        for (int k = 0; k < KK; ++k) { float e = expf(aa[k] - amax); aa[k] = e; den += e; }
        float r = 1.f / den;
        #pragma unroll
        for (int k = 0; k < KK; ++k)
            jwS[t * KK + k] = make_int2(jj[k], __float_as_int(aa[k] * r));
    }
    __syncthreads();

    // ---- epilogue constants for dims 4q..4q+3 (hoisted; same for both halves) ----
    const float rbnd = 1.0f / sqrtf(1.0f + 1e-5f);
    const float4 gb = ((const float4*)gnn_bias)[q];
    const float4 g1 = ((const float4*)bn1_g)[q];
    const float4 b1 = ((const float4*)bn1_b)[q];
    const float4 g2 = ((const float4*)bn2_g)[q];
    const float4 b2 = ((const float4*)bn2_b)[q];
    const float4 ow = ((const float4*)outW)[q];
    const float ob0 = outb[0];

    // ---- gather: each wave handles 16 nodes as 8 half-wave pairs ----
    for (int n = 0; n < 8; ++n) {
        int il = wv * 16 + 2 * n + half;  // local node 0..127
        int i  = h * 128 + il;

        float ax = 0.f, ay = 0.f, az = 0.f, aw = 0.f;
        #pragma unroll
        for (int k = 0; k < KK; ++k) {
            int2 p = jwS[il * KK + k];
            float w = __int_as_float(p.y);
            float4 xv = *(const float4*)&xls[p.x * DD + 4 * q];
            ax += w * xv.x; ay += w * xv.y; az += w * xv.z; aw += w * xv.w;
        }

        float4 em = *(const float4*)&emb[(size_t)i * DD + 4 * q];
        float o0 = (ax + gb.x) * rbnd * g1.x + b1.x; o0 = fmaxf(o0, 0.f);
        float o1 = (ay + gb.y) * rbnd * g1.y + b1.y; o1 = fmaxf(o1, 0.f);
        float o2 = (az + gb.z) * rbnd * g1.z + b1.z; o2 = fmaxf(o2, 0.f);
        float o3 = (aw + gb.w) * rbnd * g1.w + b1.w; o3 = fmaxf(o3, 0.f);
        float h0 = o0 * em.x * rbnd * g2.x + b2.x; h0 = fmaxf(h0, 0.f);
        float h1 = o1 * em.y * rbnd * g2.y + b2.y; h1 = fmaxf(h1, 0.f);
        float h2 = o2 * em.z * rbnd * g2.z + b2.z; h2 = fmaxf(h2, 0.f);
        float h3 = o3 * em.w * rbnd * g2.w + b2.w; h3 = fmaxf(h3, 0.f);

        float p4 = h0 * ow.x + h1 * ow.y + h2 * ow.z + h3 * ow.w;
        #pragma unroll
        for (int off = 16; off; off >>= 1) p4 += __shfl_xor(p4, off);
        if (q == 0) out[b * NN + i] = p4 + ob0;
    }
}

extern "C" void kernel_launch(void* const* d_in, const int* in_sizes, int n_in,
                              void* d_out, int out_size, void* d_ws, size_t ws_size,
                              hipStream_t stream) {
    const float* data     = (const float*)d_in[0];
    // d_in[1] = org_edge_index (unused, as in reference)
    const float* emb      = (const float*)d_in[2];
    const float* linW     = (const float*)d_in[3];
    const float* att_i    = (const float*)d_in[4];
    const float* att_j    = (const float*)d_in[5];
    const float* att_em_i = (const float*)d_in[6];
    const float* att_em_j = (const float*)d_in[7];
    const float* gnn_bias = (const float*)d_in[8];
    const float* bn1_g    = (const float*)d_in[9];
    const float* bn1_b    = (const float*)d_in[10];
    const float* bn2_g    = (const float*)d_in[11];
    const float* bn2_b    = (const float*)d_in[12];
    const float* outW     = (const float*)d_in[13];
    const float* outb     = (const float*)d_in[14];
    float* out = (float*)d_out;

    char* ws = (char*)d_ws;
    double* mean  = (double*)(ws + 0);                       // 2 KB
    double* nrm2  = (double*)(ws + 2048);                    // 2 KB
    float*  eemi  = (float*)(ws + 4096);                     // 1 KB
    float*  eemj  = (float*)(ws + 5120);                     // 1 KB
    int*    topk  = (int*)(ws + 8192);                       // 20 KB
    double* cov   = (double*)(ws + 32768);                   // 512 KB
    // covp: 16.78 MB at +1MB; xl (16 MB) aliases it (covp dead after k_cov_reduce).
    double* covp  = (double*)(ws + (1 << 20));
    float*  xl    = (float*)(ws + (1 << 20));
    // sil/sjl (128 KB each) reuse the cov region (cov dead after k_sim_topk).
    float*  sil   = (float*)(ws + 32768);
    float*  sjl   = (float*)(ws + 32768 + 131072);

    k_mean<<<NN, 256, 0, stream>>>(data, mean);
    k_embstats<<<NN, 128, 0, stream>>>(emb, att_em_i, att_em_j, eemi, eemj, nrm2);
    dim3 gc(NN / 64, NN / 64, SPLIT);
    k_cov5<<<gc, 256, 0, stream>>>(data, covp);
    k_cov_reduce<<<NN * NN / 256, 256, 0, stream>>>(covp, mean, cov);
    k_sim_topk<<<NN, 256, 0, stream>>>(emb, nrm2, cov, topk);
    k_xl2<<<(BB * NN) / 128, 256, 0, stream>>>(data, linW, xl);
    k_sij<<<(BB * NN) / 4, 256, 0, stream>>>(xl, att_i, att_j, eemi, eemj, sil, sjl);
    dim3 ga(2, BB);
    k_attn2<<<ga, 512, 0, stream>>>(xl, topk, sil, sjl, gnn_bias,
                                    bn1_g, bn1_b, bn2_g, bn2_b, emb, outW, outb, out);
}

// Round 8
// 115.241 us; speedup vs baseline: 7.6682x; 1.0503x over previous
//
#include <hip/hip_runtime.h>
#include <math.h>

#define BB 128
#define NN 256
#define WW 64
#define DD 128
#define KK 20
#define LL (BB*WW)   // 8192

#define SPLIT 32     // cov split-K chunks
#define BPC (BB/SPLIT) // 4 batches per chunk

// ---------------- Kernel A: per-node means of xr (row n = data[:,n,:] flattened) ----------------
__global__ void k_mean(const float* __restrict__ data, double* __restrict__ mean) {
    int n = blockIdx.x;
    int t = threadIdx.x;                  // 256 threads
    double s = 0.0;
    for (int c = 0; c < LL / 256; ++c) {
        int l = t + c * 256;
        int b = l >> 6, w = l & 63;
        s += (double)data[(b * NN + n) * WW + w];
    }
    for (int off = 32; off; off >>= 1) s += __shfl_down(s, off);
    __shared__ double red[4];
    int lane = t & 63, wid = t >> 6;
    if (lane == 0) red[wid] = s;
    __syncthreads();
    if (t == 0) mean[n] = (red[0] + red[1] + red[2] + red[3]) / (double)LL;
}

// ---------------- Kernel B: emb stats: e_em_i, e_em_j, ||emb||^2 ----------------
__global__ void k_embstats(const float* __restrict__ emb,
                           const float* __restrict__ att_em_i,
                           const float* __restrict__ att_em_j,
                           float* __restrict__ eemi, float* __restrict__ eemj,
                           double* __restrict__ nrm2) {
    int n = blockIdx.x;
    int t = threadIdx.x;                  // 128 threads
    float e = emb[n * DD + t];
    float pi = e * att_em_i[t];
    float pj = e * att_em_j[t];
    double pn = (double)e * (double)e;
    for (int off = 32; off; off >>= 1) {
        pi += __shfl_down(pi, off);
        pj += __shfl_down(pj, off);
        pn += __shfl_down(pn, off);
    }
    __shared__ float ri[2], rj[2];
    __shared__ double rn[2];
    int lane = t & 63, wid = t >> 6;
    if (lane == 0) { ri[wid] = pi; rj[wid] = pj; rn[wid] = pn; }
    __syncthreads();
    if (t == 0) { eemi[n] = ri[0] + ri[1]; eemj[n] = rj[0] + rj[1]; nrm2[n] = rn[0] + rn[1]; }
}

// ---------------- Kernel C: split-K covariance, fp32 double-buffered LDS + fp64 accumulate ------
// cov5 + LDS double buffer + reg prefetch. NO __launch_bounds__ min-waves cap: cov4's
// spill came from forcing <=128 VGPR; uncapped this sits ~130-160 VGPR, zero scratch.
// One barrier per chunk: load regs(cb+1) -> barrier -> compute buf[p] -> write buf[p^1].
__global__ __launch_bounds__(256) void k_cov7(const float* __restrict__ data,
                                              double* __restrict__ covp) {
    const int j0 = blockIdx.x * 64;
    const int i0 = blockIdx.y * 64;
    const int bz = blockIdx.z;
    const int t = threadIdx.x;
    const int ti = t >> 4, tj = t & 15;   // both 0..15

    __shared__ float As[2][64][68];       // 2 x 17 KB, pad 68 floats
    __shared__ float Bs[2][64][68];

    const int b0 = bz * BPC;
    float4 ra[4], rb[4];

    // prologue: chunk 0 -> regs -> LDS[0]
    #pragma unroll
    for (int e = 0; e < 4; ++e) {
        int idx = t + e * 256, row = idx >> 4, q = idx & 15;
        ra[e] = ((const float4*)(data + ((size_t)b0 * NN + i0 + row) * WW))[q];
        rb[e] = ((const float4*)(data + ((size_t)b0 * NN + j0 + row) * WW))[q];
    }
    #pragma unroll
    for (int e = 0; e < 4; ++e) {
        int idx = t + e * 256, row = idx >> 4, q = idx & 15;
        *(float4*)&As[0][row][4 * q] = ra[e];
        *(float4*)&Bs[0][row][4 * q] = rb[e];
    }

    double acc[4][4] = {};

    #pragma unroll 1
    for (int cb = 0; cb < BPC; ++cb) {
        const int p = cb & 1;

        // issue next chunk's global loads (held in regs across compute)
        if (cb + 1 < BPC) {
            const int nb = b0 + cb + 1;
            #pragma unroll
            for (int e = 0; e < 4; ++e) {
                int idx = t + e * 256, row = idx >> 4, q = idx & 15;
                ra[e] = ((const float4*)(data + ((size_t)nb * NN + i0 + row) * WW))[q];
                rb[e] = ((const float4*)(data + ((size_t)nb * NN + j0 + row) * WW))[q];
            }
        }

        __syncthreads();   // buf[p] writes (prologue / prev iter) visible to all

        // compute chunk cb from buf[p]: 16 k-quads, 64 fp64 FMAs each
        #pragma unroll 2
        for (int q = 0; q < 16; ++q) {
            double bd[4][4];
            #pragma unroll
            for (int c = 0; c < 4; ++c) {
                float4 bf = *(const float4*)&Bs[p][tj + 16 * c][4 * q];
                bd[c][0] = (double)bf.x; bd[c][1] = (double)bf.y;
                bd[c][2] = (double)bf.z; bd[c][3] = (double)bf.w;
            }
            #pragma unroll
            for (int r = 0; r < 4; ++r) {
                float4 af = *(const float4*)&As[p][ti + 16 * r][4 * q];
                double a0 = (double)af.x, a1 = (double)af.y;
                double a2 = (double)af.z, a3 = (double)af.w;
                #pragma unroll
                for (int c = 0; c < 4; ++c)
                    acc[r][c] += a0 * bd[c][0] + a1 * bd[c][1]
                               + a2 * bd[c][2] + a3 * bd[c][3];
            }
        }

        // write next chunk into the other buffer (safe: all waves passed this
        // iteration's barrier, so none still reads buf[p^1])
        if (cb + 1 < BPC) {
            #pragma unroll
            for (int e = 0; e < 4; ++e) {
                int idx = t + e * 256, row = idx >> 4, q = idx & 15;
                *(float4*)&As[p ^ 1][row][4 * q] = ra[e];
                *(float4*)&Bs[p ^ 1][row][4 * q] = rb[e];
            }
        }
    }

    #pragma unroll
    for (int r = 0; r < 4; ++r)
        #pragma unroll
        for (int c = 0; c < 4; ++c)
            covp[((size_t)bz * NN + i0 + ti + 16 * r) * NN + j0 + tj + 16 * c] = acc[r][c];
}

// ---------------- Kernel C2: reduce split-K partials, subtract mean term ----------------
__global__ void k_cov_reduce(const double* __restrict__ covp,
                             const double* __restrict__ mean,
                             double* __restrict__ cov) {
    int idx = blockIdx.x * 256 + threadIdx.x;   // 0..65535
    int i = idx >> 8, j = idx & 255;
    double s = 0.0;
    #pragma unroll
    for (int z = 0; z < SPLIT; ++z) s += covp[((size_t)z * NN + i) * NN + j];
    s -= (double)LL * mean[i] * mean[j];
    cov[i * NN + j] = s;
}

// ---------------- Kernel D: sim -> fp32, rank-select top-20 (stable desc, jax tie rule) --------
__global__ void k_sim_topk(const float* __restrict__ emb,
                           const double* __restrict__ nrm2,
                           const double* __restrict__ cov,
                           int* __restrict__ topk) {
    int i = blockIdx.x;
    int t = threadIdx.x;                  // 256 threads; thread t owns column j = t
    __shared__ float embI[DD];
    __shared__ float sim[NN];

    if (t < DD) embI[t] = emb[i * DD + t];
    __syncthreads();

    const float4* er = (const float4*)(emb + (size_t)t * DD);
    double dot = 0.0;
    #pragma unroll 8
    for (int d4 = 0; d4 < DD / 4; ++d4) {
        float4 v = er[d4];
        dot += (double)embI[4 * d4 + 0] * (double)v.x
             + (double)embI[4 * d4 + 1] * (double)v.y
             + (double)embI[4 * d4 + 2] * (double)v.z
             + (double)embI[4 * d4 + 3] * (double)v.w;
    }
    double cosv = dot / (sqrt(nrm2[i]) * sqrt(nrm2[t]) + 1e-8);
    double stdi = sqrt(cov[i * NN + i] + 1e-8);
    double stdj = sqrt(cov[t * NN + t] + 1e-8);
    double corrv = cov[i * NN + t] / (stdi * stdj + 1e-8);
    sim[t] = (float)(0.7 * cosv + 0.3 * corrv);
    __syncthreads();

    // rank = # elements strictly ahead of mine in (value desc, index asc) order
    float my = sim[t];
    int cnt = 0;
    #pragma unroll 8
    for (int u = 0; u < NN; ++u) {
        float s = sim[u];                 // uniform addr -> LDS broadcast, conflict-free
        cnt += (s > my || (s == my && u < t)) ? 1 : 0;
    }
    if (cnt < KK) topk[i * KK + cnt] = t;
}

// ---------------- Kernel E: xl = x @ lin_W — 128x128 tile, 8x8 register tile, float4 LDS -------
__global__ __launch_bounds__(256) void k_xl2(const float* __restrict__ data,
                                             const float* __restrict__ linW,
                                             float* __restrict__ xl) {
    const int r0 = blockIdx.x * 128;
    const int t = threadIdx.x;            // 256 threads
    const int ti = t >> 4, tj = t & 15;
    __shared__ float Xs[128][68];         // rows x k, float4-padded
    __shared__ float Wt[DD][68];          // transposed W: Wt[col][k]

    #pragma unroll
    for (int e = 0; e < 8; ++e) {
        int idx = t + e * 256, row = idx >> 4, q = idx & 15;
        float4 v = ((const float4*)(data + (size_t)(r0 + row) * WW))[q];
        *(float4*)&Xs[row][4 * q] = v;
    }
    #pragma unroll
    for (int e = 0; e < 32; ++e) {
        int idx = t + e * 256;            // idx = k*128 + col
        int k = idx >> 7, col = idx & 127;
        Wt[col][k] = linW[idx];
    }
    __syncthreads();

    float acc[8][8] = {};                 // rows 8*ti+r, cols tj+16*c
    #pragma unroll
    for (int q = 0; q < 16; ++q) {
        float4 wb[8];
        #pragma unroll
        for (int c = 0; c < 8; ++c) wb[c] = *(const float4*)&Wt[tj + 16 * c][4 * q];
        #pragma unroll
        for (int r = 0; r < 8; ++r) {
            float4 xa = *(const float4*)&Xs[8 * ti + r][4 * q];
            #pragma unroll
            for (int c = 0; c < 8; ++c)
                acc[r][c] += xa.x * wb[c].x + xa.y * wb[c].y
                           + xa.z * wb[c].z + xa.w * wb[c].w;
        }
    }
    #pragma unroll
    for (int r = 0; r < 8; ++r)
        #pragma unroll
        for (int c = 0; c < 8; ++c)
            xl[(size_t)(r0 + 8 * ti + r) * DD + tj + 16 * c] = acc[r][c];
}

// ---------------- Kernel E2: sil/sjl = xl.att_{i,j} + eem (one wave per row) ----------------
__global__ void k_sij(const float* __restrict__ xl,
                      const float* __restrict__ att_i,
                      const float* __restrict__ att_j,
                      const float* __restrict__ eemi,
                      const float* __restrict__ eemj,
                      float* __restrict__ sil, float* __restrict__ sjl) {
    int t = threadIdx.x;                  // 256 threads = 4 waves, one row each
    int lane = t & 63, wv = t >> 6;
    int v = blockIdx.x * 4 + wv;
    float x0 = xl[(size_t)v * DD + lane];
    float x1 = xl[(size_t)v * DD + 64 + lane];
    float pi = x0 * att_i[lane] + x1 * att_i[64 + lane];
    float pj = x0 * att_j[lane] + x1 * att_j[64 + lane];
    #pragma unroll
    for (int off = 32; off; off >>= 1) { pi += __shfl_down(pi, off); pj += __shfl_down(pj, off); }
    if (lane == 0) {
        int i = v & (NN - 1);
        sil[v] = pi + eemi[i];
        sjl[v] = pj + eemj[i];
    }
}

// ---------------- Kernel F: fused attention v2 ----------------
__global__ __launch_bounds__(512) void k_attn2(
        const float* __restrict__ xl, const int* __restrict__ topk,
        const float* __restrict__ sil, const float* __restrict__ sjl,
        const float* __restrict__ gnn_bias,
        const float* __restrict__ bn1_g, const float* __restrict__ bn1_b,
        const float* __restrict__ bn2_g, const float* __restrict__ bn2_b,
        const float* __restrict__ emb,
        const float* __restrict__ outW, const float* __restrict__ outb,
        float* __restrict__ out) {
    const int h = blockIdx.x;             // node half: 0 or 1
    const int b = blockIdx.y;             // batch
    const int t = threadIdx.x;            // 512 threads = 8 waves
    const int lane = t & 63, wv = t >> 6;
    const int q = lane & 31, half = lane >> 5;

    __shared__ float xls[NN * DD];        // 128 KB: xl[b]
    __shared__ int2 jwS[128 * KK];        // 20 KB: packed (j, w) per local node

    {
        const float4* src = (const float4*)(xl + (size_t)b * NN * DD);
        float4* dst = (float4*)xls;
        #pragma unroll
        for (int e = 0; e < 16; ++e) dst[t + e * 512] = src[t + e * 512];
    }

    // pre-phase: per-node softmax, scalar per thread (nodes h*128 .. h*128+127)
    if (t < 128) {
        int i = h * 128 + t;
        float si = sil[b * NN + i];
        int jj[KK]; float aa[KK];
        float amax = -3.4e38f;
        #pragma unroll
        for (int k = 0; k < KK; ++k) {
            int j = topk[i * KK + k];
            jj[k] = j;
            float a = si + sjl[b * NN + j];
            a = a > 0.f ? a : 0.2f * a;   // leaky relu
            aa[k] = a;
            amax = fmaxf(amax, a);
        }
        float den = 0.f;
        #pragma unroll
        for (int k = 0; k < KK; ++k) { float e = expf(aa[k] - amax); aa[k] = e; den += e; }
        float r = 1.f / den;
        #pragma unroll
        for (int k = 0; k < KK; ++k)
            jwS[t * KK + k] = make_int2(jj[k], __float_as_int(aa[k] * r));
    }
    __syncthreads();

    const float rbnd = 1.0f / sqrtf(1.0f + 1e-5f);
    const float4 gb = ((const float4*)gnn_bias)[q];
    const float4 g1 = ((const float4*)bn1_g)[q];
    const float4 b1 = ((const float4*)bn1_b)[q];
    const float4 g2 = ((const float4*)bn2_g)[q];
    const float4 b2 = ((const float4*)bn2_b)[q];
    const float4 ow = ((const float4*)outW)[q];
    const float ob0 = outb[0];

    for (int n = 0; n < 8; ++n) {
        int il = wv * 16 + 2 * n + half;  // local node 0..127
        int i  = h * 128 + il;

        float ax = 0.f, ay = 0.f, az = 0.f, aw = 0.f;
        #pragma unroll
        for (int k = 0; k < KK; ++k) {
            int2 p = jwS[il * KK + k];
            float w = __int_as_float(p.y);
            float4 xv = *(const float4*)&xls[p.x * DD + 4 * q];
            ax += w * xv.x; ay += w * xv.y; az += w * xv.z; aw += w * xv.w;
        }

        float4 em = *(const float4*)&emb[(size_t)i * DD + 4 * q];
        float o0 = (ax + gb.x) * rbnd * g1.x + b1.x; o0 = fmaxf(o0, 0.f);
        float o1 = (ay + gb.y) * rbnd * g1.y + b1.y; o1 = fmaxf(o1, 0.f);
        float o2 = (az + gb.z) * rbnd * g1.z + b1.z; o2 = fmaxf(o2, 0.f);
        float o3 = (aw + gb.w) * rbnd * g1.w + b1.w; o3 = fmaxf(o3, 0.f);
        float h0 = o0 * em.x * rbnd * g2.x + b2.x; h0 = fmaxf(h0, 0.f);
        float h1 = o1 * em.y * rbnd * g2.y + b2.y; h1 = fmaxf(h1, 0.f);
        float h2 = o2 * em.z * rbnd * g2.z + b2.z; h2 = fmaxf(h2, 0.f);
        float h3 = o3 * em.w * rbnd * g2.w + b2.w; h3 = fmaxf(h3, 0.f);

        float p4 = h0 * ow.x + h1 * ow.y + h2 * ow.z + h3 * ow.w;
        #pragma unroll
        for (int off = 16; off; off >>= 1) p4 += __shfl_xor(p4, off);
        if (q == 0) out[b * NN + i] = p4 + ob0;
    }
}

extern "C" void kernel_launch(void* const* d_in, const int* in_sizes, int n_in,
                              void* d_out, int out_size, void* d_ws, size_t ws_size,
                              hipStream_t stream) {
    const float* data     = (const float*)d_in[0];
    // d_in[1] = org_edge_index (unused, as in reference)
    const float* emb      = (const float*)d_in[2];
    const float* linW     = (const float*)d_in[3];
    const float* att_i    = (const float*)d_in[4];
    const float* att_j    = (const float*)d_in[5];
    const float* att_em_i = (const float*)d_in[6];
    const float* att_em_j = (const float*)d_in[7];
    const float* gnn_bias = (const float*)d_in[8];
    const float* bn1_g    = (const float*)d_in[9];
    const float* bn1_b    = (const float*)d_in[10];
    const float* bn2_g    = (const float*)d_in[11];
    const float* bn2_b    = (const float*)d_in[12];
    const float* outW     = (const float*)d_in[13];
    const float* outb     = (const float*)d_in[14];
    float* out = (float*)d_out;

    char* ws = (char*)d_ws;
    double* mean  = (double*)(ws + 0);                       // 2 KB
    double* nrm2  = (double*)(ws + 2048);                    // 2 KB
    float*  eemi  = (float*)(ws + 4096);                     // 1 KB
    float*  eemj  = (float*)(ws + 5120);                     // 1 KB
    int*    topk  = (int*)(ws + 8192);                       // 20 KB
    double* cov   = (double*)(ws + 32768);                   // 512 KB
    // covp: 16.78 MB at +1MB; xl (16 MB) aliases it (covp dead after k_cov_reduce).
    double* covp  = (double*)(ws + (1 << 20));
    float*  xl    = (float*)(ws + (1 << 20));
    // sil/sjl (128 KB each) reuse the cov region (cov dead after k_sim_topk).
    float*  sil   = (float*)(ws + 32768);
    float*  sjl   = (float*)(ws + 32768 + 131072);

    k_mean<<<NN, 256, 0, stream>>>(data, mean);
    k_embstats<<<NN, 128, 0, stream>>>(emb, att_em_i, att_em_j, eemi, eemj, nrm2);
    dim3 gc(NN / 64, NN / 64, SPLIT);
    k_cov7<<<gc, 256, 0, stream>>>(data, covp);
    k_cov_reduce<<<NN * NN / 256, 256, 0, stream>>>(covp, mean, cov);
    k_sim_topk<<<NN, 256, 0, stream>>>(emb, nrm2, cov, topk);
    k_xl2<<<(BB * NN) / 128, 256, 0, stream>>>(data, linW, xl);
    k_sij<<<(BB * NN) / 4, 256, 0, stream>>>(xl, att_i, att_j, eemi, eemj, sil, sjl);
    dim3 ga(2, BB);
    k_attn2<<<ga, 512, 0, stream>>>(xl, topk, sil, sjl, gnn_bias,
                                    bn1_g, bn1_b, bn2_g, bn2_b, emb, outW, outb, out);
}